// Round 1
// baseline (765.409 us; speedup 1.0000x reference)
//
#include <hip/hip_runtime.h>
#include <math.h>

constexpr int Nn = 64, Cc = 64, Tt = 300, Vv = 25, Ff = 64;
constexpr float ALPHA = 0.2f;
constexpr float NEG_INF = -9.0e15f;

__global__ __launch_bounds__(256) void gat_kernel(
    const float* __restrict__ x,    // (N,C,T,V)
    const int*   __restrict__ adj,  // (V,V)
    const float* __restrict__ W,    // (C,F)
    const float* __restrict__ a,    // (2F,1)
    float* __restrict__ out)        // (N,F,T,V)
{
    __shared__ float xs[Cc][Vv];    // x tile; reused as hp[F][V] in epilogue
    __shared__ float Ws[Cc][Ff];
    __shared__ float hs[Vv][Ff];    // h[v][f]
    __shared__ float att[Vv][Vv];
    __shared__ float f1s[Vv];
    __shared__ float f2s[Vv];
    __shared__ int   adjs[Vv][Vv];
    __shared__ float a1s[Ff];
    __shared__ float a2s[Ff];

    const int tid = threadIdx.x;
    const int blk = blockIdx.x;        // n*T + t
    const int n = blk / Tt;
    const int t = blk - n * Tt;

    // ---- Phase A: stage inputs to LDS ----
    const float* xb = x + (size_t)n * Cc * Tt * Vv + (size_t)t * Vv;
    for (int o = tid; o < Cc * Vv; o += 256) {
        int c = o / Vv, v = o - c * Vv;
        xs[c][v] = xb[(size_t)c * (Tt * Vv) + v];
    }
    for (int o = tid; o < Cc * Ff; o += 256)
        (&Ws[0][0])[o] = W[o];
    for (int o = tid; o < Vv * Vv; o += 256)
        (&adjs[0][0])[o] = adj[o];
    if (tid < Ff) {
        a1s[tid] = a[tid];
        a2s[tid] = a[Ff + tid];
    }
    __syncthreads();

    // ---- Phase B: h[v][f] = sum_c xs[c][v] * Ws[c][f] ----
    // 80 active threads, each computes a 5(v) x 4(f) register tile.
    if (tid < 80) {
        const int f4 = tid & 15;      // 0..15 -> f = 4*f4..4*f4+3
        const int vg = tid >> 4;      // 0..4  -> v = 5*vg..5*vg+4
        const int v0 = vg * 5;
        float4 acc[5] = {};
        for (int c = 0; c < Cc; ++c) {
            float4 w = *(const float4*)&Ws[c][f4 * 4];
            #pragma unroll
            for (int k = 0; k < 5; ++k) {
                float xv = xs[c][v0 + k];
                acc[k].x += xv * w.x;
                acc[k].y += xv * w.y;
                acc[k].z += xv * w.z;
                acc[k].w += xv * w.w;
            }
        }
        #pragma unroll
        for (int k = 0; k < 5; ++k)
            *(float4*)&hs[v0 + k][f4 * 4] = acc[k];
    }
    __syncthreads();

    // ---- Phase C: f1[i] = h[i,:]·a1 ; f2[i] = h[i,:]·a2 ----
    if (tid < 2 * Vv) {
        const int i = (tid < Vv) ? tid : tid - Vv;
        const float* av = (tid < Vv) ? a1s : a2s;
        float acc = 0.f;
        #pragma unroll 8
        for (int f = 0; f < Ff; ++f) acc += hs[i][f] * av[f];
        if (tid < Vv) f1s[i] = acc; else f2s[i] = acc;
    }
    __syncthreads();

    // ---- Phase D: masked leaky-relu + row softmax (one thread per row) ----
    if (tid < Vv) {
        const int i = tid;
        const float fi = f1s[i];
        float ev[Vv];
        float m = -INFINITY;
        #pragma unroll
        for (int j = 0; j < Vv; ++j) {
            float z = fi + f2s[j];
            z = (z > 0.f) ? z : ALPHA * z;          // leaky_relu BEFORE mask
            z = (adjs[i][j] > 0) ? z : NEG_INF;
            ev[j] = z;
            m = fmaxf(m, z);
        }
        float s = 0.f;
        #pragma unroll
        for (int j = 0; j < Vv; ++j) {
            float p = __expf(ev[j] - m);            // all-masked row -> uniform, matches jax
            ev[j] = p;
            s += p;
        }
        const float inv = 1.f / s;
        #pragma unroll
        for (int j = 0; j < Vv; ++j) att[i][j] = ev[j] * inv;
    }
    __syncthreads();

    // ---- Phase E: h'[i][f] = sum_j att[i][j] * h[j][f], then elu ----
    float (&hp)[Cc][Vv] = xs;   // reuse xs as hp[f][i] (transposed for coalesced writeout)
    if (tid < 80) {
        const int f4 = tid & 15;
        const int ig = tid >> 4;
        const int i0 = ig * 5;
        float4 acc[5] = {};
        for (int j = 0; j < Vv; ++j) {
            float4 h4 = *(const float4*)&hs[j][f4 * 4];
            #pragma unroll
            for (int k = 0; k < 5; ++k) {
                float av = att[i0 + k][j];
                acc[k].x += av * h4.x;
                acc[k].y += av * h4.y;
                acc[k].z += av * h4.z;
                acc[k].w += av * h4.w;
            }
        }
        #pragma unroll
        for (int k = 0; k < 5; ++k) {
            float vals[4] = {acc[k].x, acc[k].y, acc[k].z, acc[k].w};
            #pragma unroll
            for (int q = 0; q < 4; ++q) {
                float vv = vals[q];
                vv = (vv > 0.f) ? vv : expm1f(vv);   // elu (alpha=1)
                hp[f4 * 4 + q][i0 + k] = vv;
            }
        }
    }
    __syncthreads();

    // ---- Phase F: transposed writeout out[n,f,t,i] ----
    float* ob = out + (size_t)n * Ff * Tt * Vv + (size_t)t * Vv;
    for (int o = tid; o < Ff * Vv; o += 256) {
        int f = o / Vv, i = o - f * Vv;
        ob[(size_t)f * (Tt * Vv) + i] = hp[f][i];
    }
}

extern "C" void kernel_launch(void* const* d_in, const int* in_sizes, int n_in,
                              void* d_out, int out_size, void* d_ws, size_t ws_size,
                              hipStream_t stream) {
    const float* x   = (const float*)d_in[0];
    const int*   adj = (const int*)d_in[1];
    const float* W   = (const float*)d_in[2];
    const float* a   = (const float*)d_in[3];
    float* out = (float*)d_out;

    dim3 grid(Nn * Tt);
    dim3 block(256);
    gat_kernel<<<grid, block, 0, stream>>>(x, adj, W, a, out);
}